// Round 2
// baseline (682.776 us; speedup 1.0000x reference)
//
#include <hip/hip_runtime.h>

// ---------------------------------------------------------------------------
// AttentionFusion: 3-modality proj(+LN+ReLU) -> 3-token MHA -> gated fusion
// -> classifier.  B=16384, E=512, H=8, HD=64, NC=6.
// GEMMs: bf16 MFMA 16x16x32, fp32 accumulate (threshold is bf16-grade).
// Workspace layout is static, peak 144,834,560 B (~138 MiB) — R0's ~278 MiB
// layout is the suspected cause of the device page fault.
// ---------------------------------------------------------------------------

typedef unsigned short u16;
typedef __bf16 bf16x8 __attribute__((ext_vector_type(8)));
typedef float f32x4  __attribute__((ext_vector_type(4)));
typedef unsigned short u16x8 __attribute__((ext_vector_type(8)));
typedef unsigned short u16x4 __attribute__((ext_vector_type(4)));

#define BATCH 16384

__device__ __forceinline__ u16 f2b(float f) {   // RNE f32->bf16
  union { float f; unsigned int u; } c; c.f = f;
  unsigned int u = c.u;
  return (u16)((u + 0x7fffu + ((u >> 16) & 1u)) >> 16);
}
__device__ __forceinline__ float b2f(u16 h) {
  union { unsigned int u; float f; } c; c.u = ((unsigned int)h) << 16;
  return c.f;
}

// ---------------------------------------------------------------------------
// fp32 -> bf16 conversion for the 7 GEMM weight matrices (6.4 MB total)
// ---------------------------------------------------------------------------
struct CvtJobs {
  const float* s[7];
  u16* d[7];
  int n4[7];   // element count / 4
};

__global__ __launch_bounds__(256) void cvt_multi(CvtJobs J) {
  const int stride = gridDim.x * blockDim.x;
  const int tid = blockIdx.x * blockDim.x + threadIdx.x;
  for (int ji = 0; ji < 7; ++ji) {
    const f32x4* __restrict__ s = (const f32x4*)J.s[ji];
    u16x4* __restrict__ d = (u16x4*)J.d[ji];
    const int n4 = J.n4[ji];
    for (int i = tid; i < n4; i += stride) {
      f32x4 v = s[i];
      u16x4 o;
      #pragma unroll
      for (int c = 0; c < 4; ++c) o[c] = f2b(v[c]);
      d[i] = o;
    }
  }
}

// ---------------------------------------------------------------------------
// GEMM: C(M,N) = A(M,K) @ B(N,K)^T + bias [+ReLU].  B is bf16; A is bf16
// (ABF=1) or fp32 (ABF=0, converted to bf16 in-register after LDS read —
// avoids materializing bf16 copies of the 159 MB fp32 inputs).
// 128x128 tile, BK=32, 4 waves each 64x64 (4x4 of 16x16x32 MFMA).
// Staging via global_load_lds width=16 (LDS dst = wave base + lane*16).
// EPI: 1=bias 2=bias+relu.  OUTBF: 1=bf16 out, 0=fp32 out.
// Requires M%128==0, N%128==0, K%32==0 (true for all shapes here).
// ---------------------------------------------------------------------------
template<int ABF, int EPI, int OUTBF>
__global__ __launch_bounds__(256) void gemm_bt(
    const void* __restrict__ Av, const u16* __restrict__ Bw,
    const float* __restrict__ bias, void* __restrict__ Cv,
    int M, int N, int K)
{
  constexpr int ABYTES = ABF ? 2 : 4;
  constexpr int AROUNDS = ABF ? 2 : 4;   // 4096 B staged per round (256 lanes x 16 B)
  constexpr int AROWS   = ABF ? 64 : 32; // tile rows covered per round
  __shared__ char As[128 * 32 * ABYTES];
  __shared__ u16 Bs[128 * 32];

  const int t = threadIdx.x;
  const int m0 = blockIdx.y << 7;
  const int n0 = blockIdx.x << 7;
  const int wave = t >> 6, lane = t & 63;
  const int wm = wave & 1, wn = wave >> 1;
  const int lr  = lane & 15;          // row within 16-tile
  const int lk8 = (lane >> 4) << 3;   // k offset (quad*8)

  // staging coords: A rows are 32 elems * ABYTES; one row = {64,128} bytes
  const int arow = ABF ? (t >> 2) : (t >> 3);
  const int acol = ABF ? ((t & 3) << 4) : ((t & 7) << 4);
  const int brow = t >> 2;
  const int bcol = (t & 3) << 4;

  f32x4 acc[4][4] = {};

  const size_t rowBytesA = (size_t)K * ABYTES;
  const size_t rowBytesB = (size_t)K * 2;
  const char* Abase = (const char*)Av + (size_t)m0 * rowBytesA + acol;
  const char* Bbase = (const char*)(Bw + (size_t)n0 * K) + bcol;

  for (int k0 = 0; k0 < K; k0 += 32) {
    const char* Ak = Abase + (size_t)k0 * ABYTES;
    const char* Bk = Bbase + (size_t)k0 * 2;
    #pragma unroll
    for (int j = 0; j < AROUNDS; ++j)
      __builtin_amdgcn_global_load_lds(
          (const __attribute__((address_space(1))) void*)(Ak + (size_t)(j * AROWS + arow) * rowBytesA),
          (__attribute__((address_space(3))) void*)(As + (j << 12) + (wave << 10)),
          16, 0, 0);
    #pragma unroll
    for (int j = 0; j < 2; ++j)
      __builtin_amdgcn_global_load_lds(
          (const __attribute__((address_space(1))) void*)(Bk + (size_t)(j * 64 + brow) * rowBytesB),
          (__attribute__((address_space(3))) void*)((char*)Bs + (j << 12) + (wave << 10)),
          16, 0, 0);
    __syncthreads();   // drains vmcnt for the LDS-direct loads

    bf16x8 af[4], bfr[4];
    #pragma unroll
    for (int mi = 0; mi < 4; ++mi) {
      const int r = (wm << 6) + (mi << 4) + lr;
      if (ABF) {
        af[mi] = __builtin_bit_cast(bf16x8, *(const u16x8*)&((const u16*)As)[r * 32 + lk8]);
      } else {
        const float* Af = (const float*)As;
        f32x4 lo = *(const f32x4*)&Af[r * 32 + lk8];
        f32x4 hi = *(const f32x4*)&Af[r * 32 + lk8 + 4];
        bf16x8 v;
        #pragma unroll
        for (int d = 0; d < 4; ++d) { v[d] = (__bf16)lo[d]; v[4 + d] = (__bf16)hi[d]; }
        af[mi] = v;
      }
    }
    #pragma unroll
    for (int ni = 0; ni < 4; ++ni) {
      const int r = (wn << 6) + (ni << 4) + lr;
      bfr[ni] = __builtin_bit_cast(bf16x8, *(const u16x8*)&Bs[r * 32 + lk8]);
    }
    #pragma unroll
    for (int mi = 0; mi < 4; ++mi)
      #pragma unroll
      for (int ni = 0; ni < 4; ++ni)
        acc[mi][ni] = __builtin_amdgcn_mfma_f32_16x16x32_bf16(
            af[mi], bfr[ni], acc[mi][ni], 0, 0, 0);
    __syncthreads();
  }

  // Epilogue. C/D layout (m89-verified): col = lane&15, row = (lane>>4)*4 + reg
  const int rquad = (lane >> 4) << 2;
  #pragma unroll
  for (int ni = 0; ni < 4; ++ni) {
    const int col = n0 + (wn << 6) + (ni << 4) + lr;
    const float bv = bias[col];
    #pragma unroll
    for (int mi = 0; mi < 4; ++mi) {
      const int rowb = m0 + (wm << 6) + (mi << 4) + rquad;
      #pragma unroll
      for (int r = 0; r < 4; ++r) {
        float v = acc[mi][ni][r] + bv;
        if (EPI == 2) v = fmaxf(v, 0.0f);
        const size_t idx = (size_t)(rowb + r) * N + col;
        if (OUTBF) ((u16*)Cv)[idx] = f2b(v);
        else       ((float*)Cv)[idx] = v;
      }
    }
  }
}

// ---------------------------------------------------------------------------
// Row LayerNorm + ReLU, fp32 in -> bf16 out. One wave per row, 4 rows/block.
// ---------------------------------------------------------------------------
template<int E>
__global__ __launch_bounds__(256) void ln_relu_k(
    const float* __restrict__ src, u16* __restrict__ dst,
    const float* __restrict__ gg, const float* __restrict__ bb,
    int dstStride, int dstOff)
{
  constexpr int V = E >> 6;   // elems per lane (8 for E=512, 4 for E=256)
  const int wave = threadIdx.x >> 6, lane = threadIdx.x & 63;
  const int row = blockIdx.x * 4 + wave;
  const float* s = src + (size_t)row * E + lane * V;
  float x[V];
  float sum = 0.f, sq = 0.f;
  #pragma unroll
  for (int i = 0; i < V; i += 4) {
    f32x4 v = *(const f32x4*)(s + i);
    #pragma unroll
    for (int c = 0; c < 4; ++c) { float f = v[c]; x[i + c] = f; sum += f; sq += f * f; }
  }
  #pragma unroll
  for (int off = 32; off > 0; off >>= 1) {
    sum += __shfl_xor(sum, off);
    sq  += __shfl_xor(sq,  off);
  }
  const float invE = 1.0f / (float)E;
  const float m = sum * invE;
  const float var = sq * invE - m * m;
  const float rs = rsqrtf(var + 1e-5f);
  u16* d = dst + (size_t)row * dstStride + dstOff + lane * V;
  const float* g = gg + lane * V;
  const float* b = bb + lane * V;
  #pragma unroll
  for (int i = 0; i < V; i += 4) {
    u16x4 o;
    #pragma unroll
    for (int c = 0; c < 4; ++c) {
      float y = (x[i + c] - m) * rs * g[i + c] + b[i + c];
      o[c] = f2b(fmaxf(y, 0.0f));
    }
    *(u16x4*)(d + i) = o;
  }
}

// ---------------------------------------------------------------------------
// 3-token 8-head attention for a chunk of NB samples.
// qkv: (3*NB, 1536) bf16 rows [q|k|v]; ctx: (3*NB, 512) bf16.
// 8 lanes per (b,h), each lane owns 8 of the 64 head dims.
// ---------------------------------------------------------------------------
__global__ __launch_bounds__(256) void attn_k(
    const u16* __restrict__ qkv, u16* __restrict__ ctx)
{
  const int gid = blockIdx.x * 256 + threadIdx.x;
  const int b = gid >> 6;                 // chunk-local sample
  const int h = (threadIdx.x >> 3) & 7;
  const int ld = threadIdx.x & 7;
  const size_t rb = (size_t)(3 * b) * 1536 + h * 64 + ld * 8;

  float q[3][8], k[3][8], v[3][8];
  #pragma unroll
  for (int i = 0; i < 3; ++i) {
    u16x8 qa = *(const u16x8*)&qkv[rb + (size_t)i * 1536];
    u16x8 ka = *(const u16x8*)&qkv[rb + (size_t)i * 1536 + 512];
    u16x8 va = *(const u16x8*)&qkv[rb + (size_t)i * 1536 + 1024];
    #pragma unroll
    for (int d = 0; d < 8; ++d) { q[i][d] = b2f(qa[d]); k[i][d] = b2f(ka[d]); v[i][d] = b2f(va[d]); }
  }
  float s[9];
  #pragma unroll
  for (int i = 0; i < 3; ++i)
    #pragma unroll
    for (int j = 0; j < 3; ++j) {
      float a = 0.f;
      #pragma unroll
      for (int d = 0; d < 8; ++d) a += q[i][d] * k[j][d];
      s[i * 3 + j] = a;
    }
  #pragma unroll
  for (int m = 1; m < 8; m <<= 1)
    #pragma unroll
    for (int e = 0; e < 9; ++e) s[e] += __shfl_xor(s[e], m);

  const float sc = 0.125f;  // 1/sqrt(64)
  #pragma unroll
  for (int i = 0; i < 3; ++i) {
    const float a0 = s[i * 3 + 0] * sc, a1 = s[i * 3 + 1] * sc, a2 = s[i * 3 + 2] * sc;
    const float mx = fmaxf(a0, fmaxf(a1, a2));
    float e0 = __expf(a0 - mx), e1 = __expf(a1 - mx), e2 = __expf(a2 - mx);
    const float inv = 1.0f / (e0 + e1 + e2);
    e0 *= inv; e1 *= inv; e2 *= inv;
    u16x8 o;
    #pragma unroll
    for (int d = 0; d < 8; ++d)
      o[d] = f2b(e0 * v[0][d] + e1 * v[1][d] + e2 * v[2][d]);
    *(u16x8*)&ctx[(size_t)(3 * b + i) * 512 + h * 64 + ld * 8] = o;
  }
}

// ---------------------------------------------------------------------------
// gate2 (512->3) + softmax + gate output + weighted sum of attended rows.
// One wave per sample b.
// ---------------------------------------------------------------------------
__global__ __launch_bounds__(256) void gate_fuse_k(
    const u16* __restrict__ gateh, const float* __restrict__ gw2,
    const float* __restrict__ gb2, const u16* __restrict__ att,
    float* __restrict__ gate_out, u16* __restrict__ fused)
{
  const int wave = threadIdx.x >> 6, lane = threadIdx.x & 63;
  const int b = blockIdx.x * 4 + wave;
  float x[8];
  u16x8 xa = *(const u16x8*)&gateh[(size_t)b * 512 + lane * 8];
  #pragma unroll
  for (int d = 0; d < 8; ++d) x[d] = b2f(xa[d]);
  float s[3] = {0.f, 0.f, 0.f};
  #pragma unroll
  for (int j = 0; j < 3; ++j) {
    const float* w = gw2 + j * 512 + lane * 8;
    #pragma unroll
    for (int d = 0; d < 8; ++d) s[j] += x[d] * w[d];
  }
  #pragma unroll
  for (int m = 1; m < 64; m <<= 1)
    #pragma unroll
    for (int j = 0; j < 3; ++j) s[j] += __shfl_xor(s[j], m);
  #pragma unroll
  for (int j = 0; j < 3; ++j) s[j] += gb2[j];
  const float mx = fmaxf(s[0], fmaxf(s[1], s[2]));
  float g0 = __expf(s[0] - mx), g1 = __expf(s[1] - mx), g2 = __expf(s[2] - mx);
  const float inv = 1.0f / (g0 + g1 + g2);
  g0 *= inv; g1 *= inv; g2 *= inv;
  if (lane == 0) { gate_out[b * 3 + 0] = g0; gate_out[b * 3 + 1] = g1; gate_out[b * 3 + 2] = g2; }
  float o[8] = {};
  const float gw[3] = {g0, g1, g2};
  #pragma unroll
  for (int j = 0; j < 3; ++j) {
    u16x8 aa = *(const u16x8*)&att[(size_t)(3 * b + j) * 512 + lane * 8];
    #pragma unroll
    for (int d = 0; d < 8; ++d) o[d] += gw[j] * b2f(aa[d]);
  }
  u16x8 ov;
  #pragma unroll
  for (int d = 0; d < 8; ++d) ov[d] = f2b(o[d]);
  *(u16x8*)&fused[(size_t)b * 512 + lane * 8] = ov;
}

// ---------------------------------------------------------------------------
// classifier tail: logits = h(256) @ cw2(6,256)^T + cb2.  One wave per b.
// ---------------------------------------------------------------------------
__global__ __launch_bounds__(256) void cls2_k(
    const u16* __restrict__ hh, const float* __restrict__ cw2,
    const float* __restrict__ cb2, float* __restrict__ logits)
{
  const int wave = threadIdx.x >> 6, lane = threadIdx.x & 63;
  const int b = blockIdx.x * 4 + wave;
  float x[4];
  u16x4 xa = *(const u16x4*)&hh[(size_t)b * 256 + lane * 4];
  #pragma unroll
  for (int d = 0; d < 4; ++d) x[d] = b2f(xa[d]);
  float s[6] = {};
  #pragma unroll
  for (int j = 0; j < 6; ++j) {
    const float* w = cw2 + j * 256 + lane * 4;
    #pragma unroll
    for (int d = 0; d < 4; ++d) s[j] += x[d] * w[d];
  }
  #pragma unroll
  for (int m = 1; m < 64; m <<= 1)
    #pragma unroll
    for (int j = 0; j < 6; ++j) s[j] += __shfl_xor(s[j], m);
  if (lane < 6) logits[(size_t)b * 6 + lane] = s[lane] + cb2[lane];
}

// ---------------------------------------------------------------------------
extern "C" void kernel_launch(void* const* d_in, const int* in_sizes, int n_in,
                              void* d_out, int out_size, void* d_ws, size_t ws_size,
                              hipStream_t stream) {
  const float* rgb       = (const float*)d_in[0];
  const float* pose      = (const float*)d_in[1];
  const float* flow      = (const float*)d_in[2];
  const float* rgb_w     = (const float*)d_in[3];
  const float* rgb_b     = (const float*)d_in[4];
  const float* rgb_g     = (const float*)d_in[5];
  const float* rgb_beta  = (const float*)d_in[6];
  const float* pose_w    = (const float*)d_in[7];
  const float* pose_b    = (const float*)d_in[8];
  const float* pose_g    = (const float*)d_in[9];
  const float* pose_beta = (const float*)d_in[10];
  const float* flow_w    = (const float*)d_in[11];
  const float* flow_b    = (const float*)d_in[12];
  const float* flow_g    = (const float*)d_in[13];
  const float* flow_beta = (const float*)d_in[14];
  const float* in_w      = (const float*)d_in[15];
  const float* in_b      = (const float*)d_in[16];
  const float* out_w     = (const float*)d_in[17];
  const float* out_b     = (const float*)d_in[18];
  const float* gw1       = (const float*)d_in[19];
  const float* gb1       = (const float*)d_in[20];
  const float* gw2       = (const float*)d_in[21];
  const float* gb2       = (const float*)d_in[22];
  const float* cw1       = (const float*)d_in[23];
  const float* cb1       = (const float*)d_in[24];
  const float* cg        = (const float*)d_in[25];
  const float* cbeta     = (const float*)d_in[26];
  const float* cw2       = (const float*)d_in[27];
  const float* cb2       = (const float*)d_in[28];

  float* logits_out = (float*)d_out;                      // (16384, 6)
  float* gate_out   = (float*)d_out + (size_t)BATCH * 6;  // (16384, 3)

  // ---- static workspace layout, peak 144,834,560 B (~138 MiB) --------------
  // [0, 6.42M)            : 7 weight matrices, bf16
  // [6.42M,  +50.33M)     : rpf (B,1536)   [proj->gate1]; then att (3B,512)
  // [56.75M, +50.33M)     : ctx (3B,512)   [qkv/attn -> outproj]; then cls_tmp+h_bf
  // [107.09M,+37.75M)     : proj_tmp fp32 | qkv chunk (3*4096,1536) | gateh+fusedb
  char* ws = (char*)d_ws;
  u16* w_rgb  = (u16*)(ws + 0);
  u16* w_pose = (u16*)(ws + 786432);
  u16* w_flow = (u16*)(ws + 1441792);
  u16* w_in   = (u16*)(ws + 2490368);
  u16* w_out  = (u16*)(ws + 4063232);
  u16* w_g1   = (u16*)(ws + 4587520);
  u16* w_c1   = (u16*)(ws + 6160384);
  char* rpfB = ws + 6422528;
  char* ctxB = ws + 56754176;
  char* r1B  = ws + 107085824;

  u16*   rpf      = (u16*)rpfB;     // (B,1536) bf16 — also the (3B,512) "stacked" view
  u16*   att      = (u16*)rpfB;     // overlay: rpf dead after gate1
  u16*   ctx      = (u16*)ctxB;     // (3B,512) bf16
  float* cls_tmp  = (float*)ctxB;   // overlay: ctx dead after out-proj
  u16*   h_bf     = (u16*)(ctxB + 16777216);
  float* proj_tmp = (float*)r1B;    // (B,512) fp32, stage 2 only
  u16*   qkv_buf  = (u16*)r1B;      // (3*4096,1536) bf16, stage 3 loop
  u16*   gateh    = (u16*)r1B;      // (B,512) bf16, stage 4
  u16*   fusedb   = (u16*)(r1B + 16777216); // (B,512) bf16, stage 6

  // ---- 1. convert GEMM weights to bf16 -------------------------------------
  CvtJobs J;
  const float* srcs[7] = {rgb_w, pose_w, flow_w, in_w, out_w, gw1, cw1};
  u16* dsts[7] = {w_rgb, w_pose, w_flow, w_in, w_out, w_g1, w_c1};
  int ns[7] = {512 * 768, 512 * 640, 512 * 1024, 1536 * 512, 512 * 512, 512 * 1536, 256 * 512};
  for (int i = 0; i < 7; ++i) { J.s[i] = srcs[i]; J.d[i] = dsts[i]; J.n4[i] = ns[i] / 4; }
  cvt_multi<<<512, 256, 0, stream>>>(J);

  dim3 blk(256);
  // ---- 2. per-modality: GEMM(fp32 A, +bias) -> LN+ReLU -> rpf (interleaved)
  gemm_bt<0, 1, 0><<<dim3(4, BATCH / 128), blk, 0, stream>>>(rgb, w_rgb, rgb_b, proj_tmp, BATCH, 512, 768);
  ln_relu_k<512><<<BATCH / 4, blk, 0, stream>>>(proj_tmp, rpf, rgb_g, rgb_beta, 1536, 0);
  gemm_bt<0, 1, 0><<<dim3(4, BATCH / 128), blk, 0, stream>>>(pose, w_pose, pose_b, proj_tmp, BATCH, 512, 640);
  ln_relu_k<512><<<BATCH / 4, blk, 0, stream>>>(proj_tmp, rpf, pose_g, pose_beta, 1536, 512);
  gemm_bt<0, 1, 0><<<dim3(4, BATCH / 128), blk, 0, stream>>>(flow, w_flow, flow_b, proj_tmp, BATCH, 512, 1024);
  ln_relu_k<512><<<BATCH / 4, blk, 0, stream>>>(proj_tmp, rpf, flow_g, flow_beta, 1536, 1024);

  // ---- 3. qkv GEMM + attention, chunked over batch (4 x 4096 samples) ------
  for (int c = 0; c < 4; ++c) {
    const u16* a_chunk = rpf + (size_t)c * 4096 * 1536;       // rows 3*c*4096 of (3B,512)
    u16* ctx_chunk = ctx + (size_t)c * 4096 * 3 * 512;
    gemm_bt<1, 1, 1><<<dim3(12, 3 * 4096 / 128), blk, 0, stream>>>(
        a_chunk, w_in, in_b, qkv_buf, 3 * 4096, 1536, 512);
    attn_k<<<4096 / 4, blk, 0, stream>>>(qkv_buf, ctx_chunk);
  }

  // ---- 4. gate MLP layer 1 (B x 1536 -> 512) + ReLU (before out-proj so
  //         rpf dies and att can overlay it) --------------------------------
  gemm_bt<1, 2, 1><<<dim3(4, BATCH / 128), blk, 0, stream>>>(rpf, w_g1, gb1, gateh, BATCH, 512, 1536);

  // ---- 5. out-proj GEMM (3B x 512 -> 512), att overlays dead rpf -----------
  gemm_bt<1, 1, 1><<<dim3(4, 3 * BATCH / 128), blk, 0, stream>>>(ctx, w_out, out_b, att, 3 * BATCH, 512, 512);

  // ---- 6. gate2 + softmax + gate output + weighted fuse --------------------
  gate_fuse_k<<<BATCH / 4, blk, 0, stream>>>(gateh, gw2, gb2, att, gate_out, fusedb);

  // ---- 7. classifier: GEMM(+bias) -> LN+ReLU -> logits ---------------------
  gemm_bt<1, 1, 0><<<dim3(2, BATCH / 128), blk, 0, stream>>>(fusedb, w_c1, cb1, cls_tmp, BATCH, 256, 512);
  ln_relu_k<256><<<BATCH / 4, blk, 0, stream>>>(cls_tmp, h_bf, cg, cbeta, 256, 0);
  cls2_k<<<BATCH / 4, blk, 0, stream>>>(h_bf, cw2, cb2, logits_out);

  (void)in_sizes; (void)n_in; (void)out_size; (void)ws_size;
}